// Round 7
// baseline (216.735 us; speedup 1.0000x reference)
//
#include <hip/hip_runtime.h>

#define N_NODES 100000
#define N_EDGES 3200000
#define IN_DIM  29
#define HID_DIM 64
#define NBUCK   391            // ceil(N / 256)
#define BNODES  256            // dst nodes per bucket
#define CAP     10496          // slots/bucket (mult of 16); mean ~9650, +7.6 sigma
#define PEPT    16
#define PEPB    16384          // 1024 threads * 16 edges
#define PSTAGE  22272          // >= NBUCK*15 + PEPB = 22249

// ---- ws layout (4-byte units) ---------------------------------------------
#define OFF_CUR   0            // gcursor[NBUCK] (pad to 512)
#define OFF_ROWS  512          // rowStart[N]
#define OFF_ROWE  100512       // rowEnd[N]  (PADDED end)
#define OFF_DINV  200512       // dinv[N]
#define OFF_ZS    300512       // zs[2N+2]; row N = sentinel zeros
#define OFF_EBUF  500544       // ebuf[NBUCK*CAP] = 4,103,936
#define OFF_ACC   4604480      // acc partial h0[N*16 floats] = 6.4 MB
#define OFF_XS0   6204480      // xs0 bf16[(N+1) rows * 8 uints]  (feat 0-15)
#define OFF_XS1   7004512      // xs1 bf16[(N+1) rows * 8 uints]  (feat 16-31)

static __device__ __forceinline__ unsigned short f2bf(float f) {
    unsigned u = __float_as_uint(f);
    u += 0x7fffu + ((u >> 16) & 1u);   // RNE
    return (unsigned short)(u >> 16);
}

static __device__ __forceinline__ void unpack_add2(float2& acc, unsigned a) {
    acc.x += __uint_as_float(a << 16);
    acc.y += __uint_as_float(a & 0xFFFF0000u);
}

// -- partition: LDS counting-sort per block, FULL-LINE coalesced writeback ---
__global__ __launch_bounds__(1024) void partition_kernel(const int* __restrict__ ei,
        int* __restrict__ gcursor, int* __restrict__ ebuf) {
    __shared__ int lhist[NBUCK];
    __shared__ int lcur[NBUCK];
    __shared__ int gbase[NBUCK];
    __shared__ int soff[NBUCK];
    __shared__ int sc[NBUCK];
    __shared__ int stage[PSTAGE];                      // 87 KB
    int tid = threadIdx.x;
    for (int i = tid; i < NBUCK; i += 1024) lhist[i] = 0;
    __syncthreads();

    int base = blockIdx.x * PEPB + tid * PEPT;         // 16-aligned; E%16==0
    bool valid = (base < N_EDGES);
    if (valid) {                                       // pass 1: histogram
        const int4* dp = (const int4*)(ei + N_EDGES + base);
        #pragma unroll
        for (int q = 0; q < 4; ++q) {
            int4 t = dp[q];
            atomicAdd(&lhist[t.x >> 8], 1); atomicAdd(&lhist[t.y >> 8], 1);
            atomicAdd(&lhist[t.z >> 8], 1); atomicAdd(&lhist[t.w >> 8], 1);
        }
    }
    __syncthreads();
    int c = 0, p = 0;                                  // scan 16-padded counts
    if (tid < NBUCK) { c = lhist[tid]; p = (c + 15) & ~15; sc[tid] = p; }
    __syncthreads();
    for (int off = 1; off < NBUCK; off <<= 1) {
        int t = 0;
        if (tid < NBUCK && tid >= off) t = sc[tid - off];
        __syncthreads();
        if (tid < NBUCK) sc[tid] += t;
        __syncthreads();
    }
    if (tid < NBUCK) {
        int so = sc[tid] - p;
        soff[tid] = so;
        lcur[tid] = so;
        gbase[tid] = p ? (tid * CAP + atomicAdd(&gcursor[tid], p)) : 0; // 64B-aligned claim
    }
    __syncthreads();
    if (valid) {                                       // pass 2: place into LDS
        const int4* dp = (const int4*)(ei + N_EDGES + base);
        const int4* sp = (const int4*)(ei + base);
        #pragma unroll
        for (int q = 0; q < 4; ++q) {
            int4 d = dp[q];
            int4 s = sp[q];
            int pos;
            pos = atomicAdd(&lcur[d.x >> 8], 1); stage[pos] = s.x | ((d.x & 255) << 17);
            pos = atomicAdd(&lcur[d.y >> 8], 1); stage[pos] = s.y | ((d.y & 255) << 17);
            pos = atomicAdd(&lcur[d.z >> 8], 1); stage[pos] = s.z | ((d.z & 255) << 17);
            pos = atomicAdd(&lcur[d.w >> 8], 1); stage[pos] = s.w | ((d.w & 255) << 17);
        }
    }
    __syncthreads();
    if (tid < NBUCK) {                                 // sentinel-fill pad slots
        int endReal = lcur[tid];
        int endPad  = soff[tid] + (((lhist[tid]) + 15) & ~15);
        for (int k = endReal; k < endPad; ++k) stage[k] = -1;
    }
    __syncthreads();
    int wv = tid >> 6, ln = tid & 63;                  // full-line writeback
    for (int b = wv; b < NBUCK; b += 16) {
        int np = (lhist[b] + 15) & ~15;
        int so = soff[b], gb = gbase[b];
        for (int k = ln; k < np; k += 64)
            ebuf[gb + k] = stage[so + k];
    }
}

// ---- bucketsort: count, scan, place into LDS, coalesced writeback; ---------
// ---- builds SPLIT xs tables (32B rows: xs0 = feat 0-15, xs1 = feat 16-31) --
__global__ __launch_bounds__(1024) void bucketsort_kernel(const int* __restrict__ gcursor,
        int* __restrict__ ebuf, int* __restrict__ rowStart, int* __restrict__ rowEnd,
        float* __restrict__ dinv, const float* __restrict__ x,
        unsigned int* __restrict__ xs0, unsigned int* __restrict__ xs1,
        float* __restrict__ zs) {
    __shared__ int   cnt[BNODES];
    __shared__ int   cur[BNODES];
    __shared__ float dls[BNODES];
    __shared__ int   stage[CAP];                       // 41 KB
    __shared__ int   szp_sh;
    int b = blockIdx.x, tid = threadIdx.x;
    if (tid < BNODES) cnt[tid] = 0;
    __syncthreads();
    int base = b * CAP;
    int size = gcursor[b];                             // incl. partition pads

    for (int j = tid; j < size; j += 1024) {           // pass 1: count
        unsigned p = (unsigned)ebuf[base + j];
        if (p != 0xFFFFFFFFu) atomicAdd(&cnt[p >> 17], 1);
    }
    __syncthreads();

    int v = 0, vp = 0;
    if (tid < BNODES) { v = cnt[tid]; vp = (v + 7) & ~7; cur[tid] = vp; }
    __syncthreads();
    for (int off = 1; off < BNODES; off <<= 1) {       // inclusive scan of vp
        int t = 0;
        if (tid < BNODES && tid >= off) t = cur[tid - off];
        __syncthreads();
        if (tid < BNODES) cur[tid] += t;
        __syncthreads();
    }
    if (tid < BNODES) {
        int excl = cur[tid] - vp;
        int node = b * BNODES + tid;
        if (node < N_NODES) {
            rowStart[node] = base + excl;
            rowEnd[node]   = base + excl + vp;         // padded end
            float dn = rsqrtf((float)v + 1.0f);        // +1 = self loop (REAL deg)
            dinv[node] = dn;
            dls[tid] = dn;
        }
        if (tid == BNODES - 1) szp_sh = cur[tid];      // total node-padded size
        cur[tid] = excl;                               // becomes cursor
        for (int p2 = excl + v; p2 < excl + vp; ++p2)  // fill node-pad slots
            stage[p2] = N_NODES;                       // sentinel -> zero row
    }
    __syncthreads();

    for (int j = tid; j < size; j += 1024) {           // pass 2: place into LDS
        unsigned p = (unsigned)ebuf[base + j];
        if (p != 0xFFFFFFFFu) {
            int pos = atomicAdd(&cur[p >> 17], 1);
            stage[pos] = p & 0x1FFFF;
        }
    }
    __syncthreads();
    int szp = szp_sh;
    for (int j = tid; j < szp; j += 1024)              // coalesced writeback
        ebuf[base + j] = stage[j];

    // split xs tables: bf16(x * dinv); word kp of half h = feats 16h+2kp,+1
    for (int i = tid; i < BNODES * 16; i += 1024) {
        int dl = i >> 4, kp = i & 15;
        int nd = b * BNODES + dl;
        if (nd < N_NODES) {
            float dn = dls[dl];
            int k0 = kp * 2, k1 = k0 + 1;
            float f0 = (k0 < IN_DIM) ? x[nd * IN_DIM + k0] * dn : 0.0f;
            float f1 = (k1 < IN_DIM) ? x[nd * IN_DIM + k1] * dn : 0.0f;
            unsigned u = (unsigned)f2bf(f0) | ((unsigned)f2bf(f1) << 16);
            if (kp < 8) xs0[(size_t)nd * 8 + kp] = u;
            else        xs1[(size_t)nd * 8 + (kp - 8)] = u;
        } else if (nd == N_NODES) {
            if (kp < 8) xs0[(size_t)nd * 8 + kp] = 0u;       // sentinel rows
            else        xs1[(size_t)nd * 8 + (kp - 8)] = 0u;
        }
    }
    if (b == 0 && tid == 0) {                          // zs sentinel (agg2 pads)
        zs[2 * N_NODES]     = 0.0f;
        zs[2 * N_NODES + 1] = 0.0f;
    }
}

// --- fused two-phase: 32B rows -> per-phase table is L2-resident (3.2 MB) ---
#define XROWU(i) (((unsigned)(i) << 5) | moff)

#define PREP(P, rs, re, node)                                            \
    int P##i0, P##i1, P##i2, P##i3, P##i4, P##i5;                        \
    {                                                                    \
        int relim = max((re) - 1, (rs));                                 \
        int j0 = (rs) + q;                                               \
        int t0 = ebuf[min(j0,      relim)];                              \
        int t1 = ebuf[min(j0 + 8,  relim)];                              \
        int t2 = ebuf[min(j0 + 16, relim)];                              \
        int t3 = ebuf[min(j0 + 24, relim)];                              \
        int t4 = ebuf[min(j0 + 32, relim)];                              \
        P##i0 = (j0      < (re)) ? t0 : N_NODES;                         \
        P##i1 = (j0 + 8  < (re)) ? t1 : N_NODES;                         \
        P##i2 = (j0 + 16 < (re)) ? t2 : N_NODES;                         \
        P##i3 = (j0 + 24 < (re)) ? t3 : N_NODES;                         \
        P##i4 = (j0 + 32 < (re)) ? t4 : N_NODES;                         \
        P##i5 = (q == 0) ? (node) : N_NODES;   /* self loop as slot 6 */ \
    }

#define GATHU(G, P)                                                      \
    unsigned G##0 = *(const unsigned*)(xb + XROWU(P##i0));               \
    unsigned G##1 = *(const unsigned*)(xb + XROWU(P##i1));               \
    unsigned G##2 = *(const unsigned*)(xb + XROWU(P##i2));               \
    unsigned G##3 = *(const unsigned*)(xb + XROWU(P##i3));               \
    unsigned G##4 = *(const unsigned*)(xb + XROWU(P##i4));               \
    unsigned G##5 = *(const unsigned*)(xb + XROWU(P##i5));

#define UNPU(acc, G)                                                     \
    unpack_add2(acc, G##0); unpack_add2(acc, G##1); unpack_add2(acc, G##2); \
    unpack_add2(acc, G##3); unpack_add2(acc, G##4); unpack_add2(acc, G##5);

#define TAILU(acc, rs, re)                                               \
    {                                                                    \
        int j = (rs) + q + 40;                                           \
        while (j < (re)) {            /* wave-uniform trip count */      \
            int s = ebuf[j];                                             \
            unsigned a = *(const unsigned*)(xb + XROWU(s));              \
            unpack_add2(acc, a);                                         \
            j += 8;                                                      \
        }                                                                \
    }

#define FOLD2(acc)                                                       \
    acc.x += __shfl_xor(acc.x, 8);  acc.y += __shfl_xor(acc.y, 8);       \
    acc.x += __shfl_xor(acc.x, 16); acc.y += __shfl_xor(acc.y, 16);      \
    acc.x += __shfl_xor(acc.x, 32); acc.y += __shfl_xor(acc.y, 32);

// final MLP for two nodes, pre-folded float4 acc (x,y=feat 2m,2m+1; z,w=16+2m,17+2m)
static __device__ __forceinline__ void mlp2_fin(float4 aA, float4 aB,
        int nodeA, int nodeB, int lane, float dnA, float dnB,
        const float* w1s, const float* b1s, const float* w2s,
        float* __restrict__ zs) {
    aA.x *= dnA; aA.y *= dnA; aA.z *= dnA; aA.w *= dnA;
    aB.x *= dnB; aB.y *= dnB; aB.z *= dnB; aB.w *= dnB;
    float hA = b1s[lane], hB = b1s[lane];
    #pragma unroll
    for (int kk = 0; kk < IN_DIM; ++kk) {              // shared weight read
        float w = w1s[kk * HID_DIM + lane];
        float cA = (kk < 16) ? ((kk & 1) ? aA.y : aA.x)
                             : ((kk & 1) ? aA.w : aA.z);
        float cB = (kk < 16) ? ((kk & 1) ? aB.y : aB.x)
                             : ((kk & 1) ? aB.w : aB.z);
        hA = fmaf(__shfl(cA, (kk >> 1) & 7), w, hA);
        hB = fmaf(__shfl(cB, (kk >> 1) & 7), w, hB);
    }
    hA = fmaxf(hA, 0.0f); hB = fmaxf(hB, 0.0f);
    float zA0 = hA * w2s[lane * 2 + 0], zA1 = hA * w2s[lane * 2 + 1];
    float zB0 = hB * w2s[lane * 2 + 0], zB1 = hB * w2s[lane * 2 + 1];
    #pragma unroll
    for (int off = 32; off > 0; off >>= 1) {
        zA0 += __shfl_down(zA0, off); zA1 += __shfl_down(zA1, off);
        zB0 += __shfl_down(zB0, off); zB1 += __shfl_down(zB1, off);
    }
    if (lane == 0) {                                   // pre-scale by src dinv
        float2 oA; oA.x = zA0 * dnA; oA.y = zA1 * dnA;
        float2 oB; oB.x = zB0 * dnB; oB.y = zB1 * dnB;
        *(float2*)(zs + nodeA * 2) = oA;
        *(float2*)(zs + nodeB * 2) = oB;
    }
}

template<int PHASE>
__global__ __launch_bounds__(512) void fused_kernel(const unsigned int* __restrict__ xs_,
        const int* __restrict__ rowStart, const int* __restrict__ rowEnd,
        const int* __restrict__ ebuf, const float* __restrict__ dinv,
        const float* __restrict__ W1, const float* __restrict__ b1,
        const float* __restrict__ W2, float* __restrict__ accb,
        float* __restrict__ zs) {
    __shared__ float w1s[IN_DIM * HID_DIM];
    __shared__ float b1s[HID_DIM];
    __shared__ float w2s[HID_DIM * 2];
    const int tid = threadIdx.x;
    if (PHASE == 1) {
        for (int i = tid; i < IN_DIM * HID_DIM; i += 512) w1s[i] = W1[i];
        if (tid < HID_DIM) {
            b1s[tid] = b1[tid];
            w2s[tid * 2 + 0] = W2[tid * 2 + 0];
            w2s[tid * 2 + 1] = W2[tid * 2 + 1];
        }
        __syncthreads();
    }

    const int lane = tid & 63;
    const int q = lane >> 3, m = lane & 7;             // 8 streams x 8 lanes
    const unsigned moff = (unsigned)(m << 2);          // byte offset in 32B row
    const char* xb = (const char*)xs_;
    const int n0 = blockIdx.x * 32 + (tid >> 6) * 4;   // 8 waves x 4 nodes; 3125*32=N

    const int rs0 = rowStart[n0+0], re0 = rowEnd[n0+0];
    const int rs1 = rowStart[n0+1], re1 = rowEnd[n0+1];
    const int rs2 = rowStart[n0+2], re2 = rowEnd[n0+2];
    const int rs3 = rowStart[n0+3], re3 = rowEnd[n0+3];

    PREP(pa, rs0, re0, n0+0)
    PREP(pb, rs1, re1, n0+1)
    GATHU(ga, pa)
    GATHU(gb, pb)
    PREP(pc, rs2, re2, n0+2)
    PREP(pd, rs3, re3, n0+3)
    float2 a0 = make_float2(0.f, 0.f), a1 = make_float2(0.f, 0.f);
    UNPU(a0, ga)
    TAILU(a0, rs0, re0)
    UNPU(a1, gb)
    TAILU(a1, rs1, re1)
    GATHU(gc, pc)
    GATHU(gd, pd)
    FOLD2(a0)
    FOLD2(a1)
    float2 a2 = make_float2(0.f, 0.f), a3 = make_float2(0.f, 0.f);
    UNPU(a2, gc)
    TAILU(a2, rs2, re2)
    UNPU(a3, gd)
    TAILU(a3, rs3, re3)
    FOLD2(a2)
    FOLD2(a3)

    if (PHASE == 0) {                                  // store raw partials
        if (q == 0) {
            float2* ap = (float2*)accb;
            ap[(n0+0) * 8 + m] = a0;
            ap[(n0+1) * 8 + m] = a1;
            ap[(n0+2) * 8 + m] = a2;
            ap[(n0+3) * 8 + m] = a3;
        }
    } else {                                           // combine + MLP
        const float2* ap = (const float2*)accb;
        float2 h0a = ap[(n0+0) * 8 + m];
        float2 h0b = ap[(n0+1) * 8 + m];
        float2 h0c = ap[(n0+2) * 8 + m];
        float2 h0d = ap[(n0+3) * 8 + m];
        float dn0 = dinv[n0+0], dn1 = dinv[n0+1];
        float dn2 = dinv[n0+2], dn3 = dinv[n0+3];
        float4 A0; A0.x = h0a.x; A0.y = h0a.y; A0.z = a0.x; A0.w = a0.y;
        float4 A1; A1.x = h0b.x; A1.y = h0b.y; A1.z = a1.x; A1.w = a1.y;
        float4 A2; A2.x = h0c.x; A2.y = h0c.y; A2.z = a2.x; A2.w = a2.y;
        float4 A3; A3.x = h0d.x; A3.y = h0d.y; A3.z = a3.x; A3.w = a3.y;
        mlp2_fin(A0, A1, n0+0, n0+1, lane, dn0, dn1, w1s, b1s, w2s, zs);
        mlp2_fin(A2, A3, n0+2, n0+3, lane, dn2, dn3, w1s, b1s, w2s, zs);
    }
}

// ------- agg2: 16-lane group per node gathers zs (2x unroll) + finalize -----
__global__ __launch_bounds__(256) void agg2_kernel(const float* __restrict__ zs,
        const int* __restrict__ rowStart, const int* __restrict__ rowEnd,
        const int* __restrict__ ebuf, const float* __restrict__ dinv,
        const float* __restrict__ b2, float* __restrict__ out) {
    int tid = threadIdx.x;
    int node = blockIdx.x * 16 + (tid >> 4);
    if (node >= N_NODES) return;
    int gl = tid & 15;
    const float2* zs2 = (const float2*)zs;
    float a0 = 0.0f, a1 = 0.0f, c0 = 0.0f, c1 = 0.0f;
    int rs = rowStart[node], re = rowEnd[node];
    int j = rs + gl;
    for (; j + 16 < re; j += 32) {
        float2 za = zs2[ebuf[j]];
        float2 zb = zs2[ebuf[j + 16]];
        a0 += za.x; a1 += za.y;
        c0 += zb.x; c1 += zb.y;
    }
    if (j < re) {
        float2 za = zs2[ebuf[j]];
        a0 += za.x; a1 += za.y;
    }
    a0 += c0; a1 += c1;
    a0 += __shfl_xor(a0, 8); a1 += __shfl_xor(a1, 8);
    a0 += __shfl_xor(a0, 4); a1 += __shfl_xor(a1, 4);
    a0 += __shfl_xor(a0, 2); a1 += __shfl_xor(a1, 2);
    a0 += __shfl_xor(a0, 1); a1 += __shfl_xor(a1, 1);
    if (gl == 0) {
        float dn = dinv[node];
        float2 zself = zs2[node];
        float2 o;
        o.x = dn * (a0 + zself.x) + b2[0];
        o.y = dn * (a1 + zself.y) + b2[1];
        ((float2*)out)[node] = o;
    }
}

extern "C" void kernel_launch(void* const* d_in, const int* in_sizes, int n_in,
                              void* d_out, int out_size, void* d_ws, size_t ws_size,
                              hipStream_t stream) {
    const float* x  = (const float*)d_in[0];
    const int*   ei = (const int*)d_in[1];
    const float* W1 = (const float*)d_in[2];
    const float* b1 = (const float*)d_in[3];
    const float* W2 = (const float*)d_in[4];
    const float* b2 = (const float*)d_in[5];
    float* out = (float*)d_out;

    int*   wsi      = (int*)d_ws;
    float* wsf      = (float*)d_ws;
    int*   gcursor  = wsi + OFF_CUR;
    int*   rowStart = wsi + OFF_ROWS;
    int*   rowEnd   = wsi + OFF_ROWE;
    float* dinv     = wsf + OFF_DINV;
    float* zs       = wsf + OFF_ZS;
    int*   ebuf     = wsi + OFF_EBUF;
    float* accb     = wsf + OFF_ACC;
    unsigned int* xs0 = (unsigned int*)(wsi + OFF_XS0);
    unsigned int* xs1 = (unsigned int*)(wsi + OFF_XS1);

    hipMemsetAsync(gcursor, 0, NBUCK * sizeof(int), stream);
    partition_kernel<<<(N_EDGES + PEPB - 1) / PEPB, 1024, 0, stream>>>(ei, gcursor, ebuf);
    bucketsort_kernel<<<NBUCK, 1024, 0, stream>>>(gcursor, ebuf, rowStart, rowEnd, dinv, x, xs0, xs1, zs);
    fused_kernel<0><<<N_NODES / 32, 512, 0, stream>>>(xs0, rowStart, rowEnd, ebuf, dinv, W1, b1, W2, accb, zs);
    fused_kernel<1><<<N_NODES / 32, 512, 0, stream>>>(xs1, rowStart, rowEnd, ebuf, dinv, W1, b1, W2, accb, zs);
    agg2_kernel<<<(N_NODES + 15) / 16, 256, 0, stream>>>(zs, rowStart, rowEnd, ebuf, dinv, b2, out);
}